// Round 9
// baseline (107.875 us; speedup 1.0000x reference)
//
#include <hip/hip_runtime.h>

#define Kc 512
#define Dc 64
#define Hc 64
#define Bc 16
#define Tc 16384
#define Nt (Bc * Tc)              // 262144 tokens
#define LN_EPS 1e-5f
// loss = (1 + 0.25) * mean over N*D elements
#define LOSS_SCALE (1.25f / 16777216.0f)   // 1.25 / (Nt*Dc)

#define QG_BLOCKS 16384           // Nt*16/256: one float4 per thread
#define IL_BLOCKS 256             // idx+loss kernel
#define IL_TOKENS_PER_THREAD 4    // 256*256*4 = Nt
#define N_PARTIALS (IL_BLOCKS * 4)  // per-wave partials, no barrier

// ---------------------------------------------------------------------------
// Kernel 1: per-t-value table precompute (R7 coalesced version — WIN, keep).
// ---------------------------------------------------------------------------
__global__ __launch_bounds__(256) void precompute_kernel(
    const float* __restrict__ W1, const float* __restrict__ b1,
    const float* __restrict__ ln_g, const float* __restrict__ ln_b,
    const float* __restrict__ W2, const float* __restrict__ b2,
    const float* __restrict__ cb,
    float* __restrict__ q_table, float* __restrict__ idxf_table,
    float* __restrict__ d2_table)
{
    const int v   = blockIdx.x;      // t value, 0..511
    const int tid = threadIdx.x;     // 0..255
    const int lane = tid & 63;
    const int wave = tid >> 6;       // 0..3

    __shared__ float s_h[Hc];
    __shared__ __align__(16) float s_z[Dc];
    __shared__ float s_bd[4];
    __shared__ int   s_bk[4];
    __shared__ int   s_win;
    __shared__ float s_wd;

    // ---- encoder on the first wave only (lane = H index = D index) ----
    if (tid < 64) {
        const float norm_t = (float)v * (2.0f / (float)(Kc - 1)) - 1.0f;
        float h = norm_t * W1[lane] + b1[lane];

        float s = h;
        #pragma unroll
        for (int o = 32; o > 0; o >>= 1) s += __shfl_xor(s, o);
        const float mu = s * (1.0f / (float)Hc);
        const float d = h - mu;
        float vs = d * d;
        #pragma unroll
        for (int o = 32; o > 0; o >>= 1) vs += __shfl_xor(vs, o);
        const float var = vs * (1.0f / (float)Hc);
        float hn = d * rsqrtf(var + LN_EPS) * ln_g[lane] + ln_b[lane];
        hn = fmaxf(hn, 0.0f);
        s_h[lane] = hn;
        __builtin_amdgcn_s_waitcnt(0);   // LDS write visible within wave
        float z = b2[lane];
        #pragma unroll
        for (int hh = 0; hh < Hc; ++hh) z = fmaf(s_h[hh], W2[hh * Dc + lane], z);
        s_z[lane] = z;
    }
    __syncthreads();

    // ---- coalesced argmin: wave reads 64 consecutive float4s/iter ----
    const float4* cb4 = (const float4*)cb;
    const float4 zz = ((const float4*)s_z)[lane & 15];   // loop-invariant
    const int rowgrp = lane >> 4;                        // 0..3

    float best_d = 3.4e38f;
    int best_k = 0;
    const int base = wave * 2048;
    #pragma unroll 4
    for (int i = 0; i < 32; ++i) {
        const float4 e = cb4[base + i * 64 + lane];
        float d0 = zz.x - e.x, d1 = zz.y - e.y, d2 = zz.z - e.z, d3 = zz.w - e.w;
        float pd = d0 * d0;
        pd = fmaf(d1, d1, pd); pd = fmaf(d2, d2, pd); pd = fmaf(d3, d3, pd);
        pd += __shfl_xor(pd, 1);
        pd += __shfl_xor(pd, 2);
        pd += __shfl_xor(pd, 4);
        pd += __shfl_xor(pd, 8);
        const int k = wave * 128 + i * 4 + rowgrp;
        if (pd < best_d) { best_d = pd; best_k = k; }  // k ascends per lane
    }
    #pragma unroll
    for (int o = 32; o > 0; o >>= 1) {
        const float od = __shfl_xor(best_d, o);
        const int   ok = __shfl_xor(best_k, o);
        if (od < best_d || (od == best_d && ok < best_k)) { best_d = od; best_k = ok; }
    }
    if (lane == 0) { s_bd[wave] = best_d; s_bk[wave] = best_k; }
    __syncthreads();
    if (tid == 0) {
        float bd = s_bd[0]; int bk = s_bk[0];
        #pragma unroll
        for (int w = 1; w < 4; ++w) {
            const float od = s_bd[w]; const int ok = s_bk[w];
            if (od < bd || (od == bd && ok < bk)) { bd = od; bk = ok; }
        }
        s_win = bk; s_wd = bd;
    }
    __syncthreads();

    if (tid < 64) q_table[v * Dc + tid] = cb[s_win * Dc + tid];
    if (tid == 0) { idxf_table[v] = (float)s_win; d2_table[v] = s_wd; }
}

// ---------------------------------------------------------------------------
// Kernel 2: pure-stream q gather. 16384 blocks x 256, ONE float4 per thread.
// No LDS, no barrier, no idx/loss interleave — minimal dependent chain.
// R4/R2 showed BW scales with block count (1024->953GB/s, 4096->1.9TB/s):
// concurrency-limited, so go to max blocks and strip block-exit gating.
// ---------------------------------------------------------------------------
__global__ __launch_bounds__(256) void qgather_kernel(
    const int* __restrict__ t, const float* __restrict__ q_table,
    float* __restrict__ out_q)
{
    const int g     = blockIdx.x * 256 + threadIdx.x;   // float4 index
    const int tv    = t[g >> 4];                        // broadcast per 16 lanes
    const int part  = g & 15;
    ((float4*)out_q)[g] = ((const float4*)q_table)[(tv << 4) + part];
}

// ---------------------------------------------------------------------------
// Kernel 3: idx + loss partials. 256 blocks x 256, 4 tokens/thread,
// per-WAVE partials (no __syncthreads, no LDS). ~2MB traffic.
// ---------------------------------------------------------------------------
__global__ __launch_bounds__(256) void idxloss_kernel(
    const int* __restrict__ t, const float* __restrict__ idxf_table,
    const float* __restrict__ d2_table,
    float* __restrict__ out_idx, float* __restrict__ partials)
{
    const int tid0 = blockIdx.x * 256 + threadIdx.x;
    float lsum = 0.0f;
    #pragma unroll
    for (int i = 0; i < IL_TOKENS_PER_THREAD; ++i) {
        const int token = tid0 + i * (IL_BLOCKS * 256);   // coalesced
        const int tv = t[token];
        out_idx[token] = idxf_table[tv];
        lsum += d2_table[tv];
    }
    #pragma unroll
    for (int o = 32; o > 0; o >>= 1) lsum += __shfl_xor(lsum, o);
    if ((threadIdx.x & 63) == 0)
        partials[blockIdx.x * 4 + (threadIdx.x >> 6)] = lsum;
}

// ---------------------------------------------------------------------------
// Kernel 4: reduce 1024 per-wave partials -> loss. Single block.
// ---------------------------------------------------------------------------
__global__ __launch_bounds__(256) void loss_reduce_kernel(
    const float* __restrict__ partials, float* __restrict__ out_loss)
{
    const int tid = threadIdx.x;
    float s = 0.0f;
    #pragma unroll
    for (int i = 0; i < N_PARTIALS / 256; ++i)
        s += partials[i * 256 + tid];
    #pragma unroll
    for (int o = 32; o > 0; o >>= 1) s += __shfl_xor(s, o);
    __shared__ float s_partial[4];
    if ((tid & 63) == 0) s_partial[tid >> 6] = s;
    __syncthreads();
    if (tid == 0)
        out_loss[0] = (s_partial[0] + s_partial[1] + s_partial[2] + s_partial[3])
                      * LOSS_SCALE;
}

extern "C" void kernel_launch(void* const* d_in, const int* in_sizes, int n_in,
                              void* d_out, int out_size, void* d_ws, size_t ws_size,
                              hipStream_t stream) {
    const int*   t        = (const int*)d_in[0];     // [B,T,1] int32
    const float* W1       = (const float*)d_in[1];   // [1,H]
    const float* b1       = (const float*)d_in[2];   // [H]
    const float* ln_g     = (const float*)d_in[3];   // [H]
    const float* ln_b     = (const float*)d_in[4];   // [H]
    const float* W2       = (const float*)d_in[5];   // [H,D]
    const float* b2       = (const float*)d_in[6];   // [D]
    const float* codebook = (const float*)d_in[7];   // [K,D]

    float* out      = (float*)d_out;
    float* out_q    = out;                     // Nt*Dc floats
    float* out_idx  = out + (size_t)Nt * Dc;   // Nt floats (idx as float)
    float* out_loss = out_idx + Nt;            // 1 float

    float* ws        = (float*)d_ws;
    float* q_table   = ws;                        // 512*64
    float* idxf_tab  = ws + Kc * Dc;              // 512
    float* d2_tab    = idxf_tab + Kc;             // 512
    float* partials  = d2_tab + Kc;               // 1024

    precompute_kernel<<<Kc, 256, 0, stream>>>(
        W1, b1, ln_g, ln_b, W2, b2, codebook,
        q_table, idxf_tab, d2_tab);

    qgather_kernel<<<QG_BLOCKS, 256, 0, stream>>>(t, q_table, out_q);

    idxloss_kernel<<<IL_BLOCKS, 256, 0, stream>>>(
        t, idxf_tab, d2_tab, out_idx, partials);

    loss_reduce_kernel<<<1, 256, 0, stream>>>(partials, out_loss);
}

// Round 10
// 104.739 us; speedup vs baseline: 1.0299x; 1.0299x over previous
//
#include <hip/hip_runtime.h>

#define Kc 512
#define Dc 64
#define Hc 64
#define Bc 16
#define Tc 16384
#define Nt (Bc * Tc)              // 262144 tokens
#define LN_EPS 1e-5f
// loss = (1 + 0.25) * mean over N*D elements
#define LOSS_SCALE (1.25f / 16777216.0f)   // 1.25 / (Nt*Dc)

#define QG_BLOCKS 256             // 1 block per CU
#define QG_THREADS 1024           // 16 waves
#define QG_ITERS 16               // 256*1024*16 = 4,194,304 float4s = Nt*16
#define N_PARTIALS (QG_BLOCKS * 16)   // per-wave partials = 4096

// ---------------------------------------------------------------------------
// Kernel 1: per-t-value table precompute (R7 coalesced version — WIN, keep).
// ---------------------------------------------------------------------------
__global__ __launch_bounds__(256) void precompute_kernel(
    const float* __restrict__ W1, const float* __restrict__ b1,
    const float* __restrict__ ln_g, const float* __restrict__ ln_b,
    const float* __restrict__ W2, const float* __restrict__ b2,
    const float* __restrict__ cb,
    float* __restrict__ q_table, float* __restrict__ idxf_table,
    float* __restrict__ d2_table)
{
    const int v   = blockIdx.x;      // t value, 0..511
    const int tid = threadIdx.x;     // 0..255
    const int lane = tid & 63;
    const int wave = tid >> 6;       // 0..3

    __shared__ float s_h[Hc];
    __shared__ __align__(16) float s_z[Dc];
    __shared__ float s_bd[4];
    __shared__ int   s_bk[4];
    __shared__ int   s_win;
    __shared__ float s_wd;

    // ---- encoder on the first wave only (lane = H index = D index) ----
    if (tid < 64) {
        const float norm_t = (float)v * (2.0f / (float)(Kc - 1)) - 1.0f;
        float h = norm_t * W1[lane] + b1[lane];

        float s = h;
        #pragma unroll
        for (int o = 32; o > 0; o >>= 1) s += __shfl_xor(s, o);
        const float mu = s * (1.0f / (float)Hc);
        const float d = h - mu;
        float vs = d * d;
        #pragma unroll
        for (int o = 32; o > 0; o >>= 1) vs += __shfl_xor(vs, o);
        const float var = vs * (1.0f / (float)Hc);
        float hn = d * rsqrtf(var + LN_EPS) * ln_g[lane] + ln_b[lane];
        hn = fmaxf(hn, 0.0f);
        s_h[lane] = hn;
        __builtin_amdgcn_s_waitcnt(0);   // LDS write visible within wave
        float z = b2[lane];
        #pragma unroll
        for (int hh = 0; hh < Hc; ++hh) z = fmaf(s_h[hh], W2[hh * Dc + lane], z);
        s_z[lane] = z;
    }
    __syncthreads();

    // ---- coalesced argmin: wave reads 64 consecutive float4s/iter ----
    const float4* cb4 = (const float4*)cb;
    const float4 zz = ((const float4*)s_z)[lane & 15];   // loop-invariant
    const int rowgrp = lane >> 4;                        // 0..3

    float best_d = 3.4e38f;
    int best_k = 0;
    const int base = wave * 2048;
    #pragma unroll 4
    for (int i = 0; i < 32; ++i) {
        const float4 e = cb4[base + i * 64 + lane];
        float d0 = zz.x - e.x, d1 = zz.y - e.y, d2 = zz.z - e.z, d3 = zz.w - e.w;
        float pd = d0 * d0;
        pd = fmaf(d1, d1, pd); pd = fmaf(d2, d2, pd); pd = fmaf(d3, d3, pd);
        pd += __shfl_xor(pd, 1);
        pd += __shfl_xor(pd, 2);
        pd += __shfl_xor(pd, 4);
        pd += __shfl_xor(pd, 8);
        const int k = wave * 128 + i * 4 + rowgrp;
        if (pd < best_d) { best_d = pd; best_k = k; }  // k ascends per lane
    }
    #pragma unroll
    for (int o = 32; o > 0; o >>= 1) {
        const float od = __shfl_xor(best_d, o);
        const int   ok = __shfl_xor(best_k, o);
        if (od < best_d || (od == best_d && ok < best_k)) { best_d = od; best_k = ok; }
    }
    if (lane == 0) { s_bd[wave] = best_d; s_bk[wave] = best_k; }
    __syncthreads();
    if (tid == 0) {
        float bd = s_bd[0]; int bk = s_bk[0];
        #pragma unroll
        for (int w = 1; w < 4; ++w) {
            const float od = s_bd[w]; const int ok = s_bk[w];
            if (od < bd || (od == bd && ok < bk)) { bd = od; bk = ok; }
        }
        s_win = bk; s_wd = bd;
    }
    __syncthreads();

    if (tid < 64) q_table[v * Dc + tid] = cb[s_win * Dc + tid];
    if (tid == 0) { idxf_table[v] = (float)s_win; d2_table[v] = s_wd; }
}

// ---------------------------------------------------------------------------
// Kernel 2: LDS-staged gather + idx + loss partials. 256 blocks x 1024 thr
// (1 block/CU; 132 KB LDS of the 160 KB/CU). Stage the whole 128 KB q_table
// + this block's 4 KB t-slice into LDS once; the store loop is then
// LDS-read -> global-store, 16 independent iters/thread — removes the
// ~200-900cy global-load dependency that capped the old gather at ~2 TB/s
// (R8: store path exonerated; R9: block concurrency exonerated).
// ---------------------------------------------------------------------------
__global__ __launch_bounds__(QG_THREADS) void qgather_kernel(
    const int* __restrict__ t, const float* __restrict__ q_table,
    const float* __restrict__ idxf_table, const float* __restrict__ d2_table,
    float* __restrict__ out_q, float* __restrict__ out_idx,
    float* __restrict__ partials)
{
    __shared__ __align__(16) float s_q[Kc * Dc];   // 128 KB
    __shared__ int s_t[QG_THREADS];                // 4 KB
    const int tid = threadIdx.x;

    // stage table: 8 coalesced float4 rounds x 1024 threads = 32768 f4
    float4* s_q4 = (float4*)s_q;
    const float4* q4 = (const float4*)q_table;
    #pragma unroll
    for (int i = 0; i < (Kc * Dc / 4) / QG_THREADS; ++i)
        s_q4[i * QG_THREADS + tid] = q4[i * QG_THREADS + tid];
    // stage this block's t slice
    const int tokbase = blockIdx.x * QG_THREADS;
    s_t[tid] = t[tokbase + tid];
    __syncthreads();

    const int f4base = tokbase * 16;
    const int part = tid & 15;           // invariant across iters (1024%16==0)
    float lsum = 0.0f;
    #pragma unroll
    for (int i = 0; i < QG_ITERS; ++i) {
        const int o = i * QG_THREADS + tid;      // 0..16383 within block
        const int ltok = o >> 4;                 // 0..1023
        const int tv = s_t[ltok];                // LDS broadcast per 16 lanes
        ((float4*)out_q)[f4base + o] = s_q4[(tv << 4) + part];  // LDS->global
        if (part == 0) {                         // each ltok exactly once
            const int token = tokbase + ltok;
            out_idx[token] = idxf_table[tv];
            lsum += d2_table[tv];
        }
    }

    // per-wave partial (no extra barrier)
    #pragma unroll
    for (int o = 32; o > 0; o >>= 1) lsum += __shfl_xor(lsum, o);
    if ((tid & 63) == 0)
        partials[blockIdx.x * (QG_THREADS / 64) + (tid >> 6)] = lsum;
}

// ---------------------------------------------------------------------------
// Kernel 3: reduce 4096 per-wave partials -> loss. Single block.
// ---------------------------------------------------------------------------
__global__ __launch_bounds__(256) void loss_reduce_kernel(
    const float* __restrict__ partials, float* __restrict__ out_loss)
{
    const int tid = threadIdx.x;
    float s = 0.0f;
    #pragma unroll
    for (int i = 0; i < N_PARTIALS / 256; ++i)
        s += partials[i * 256 + tid];
    #pragma unroll
    for (int o = 32; o > 0; o >>= 1) s += __shfl_xor(s, o);
    __shared__ float s_partial[4];
    if ((tid & 63) == 0) s_partial[tid >> 6] = s;
    __syncthreads();
    if (tid == 0)
        out_loss[0] = (s_partial[0] + s_partial[1] + s_partial[2] + s_partial[3])
                      * LOSS_SCALE;
}

extern "C" void kernel_launch(void* const* d_in, const int* in_sizes, int n_in,
                              void* d_out, int out_size, void* d_ws, size_t ws_size,
                              hipStream_t stream) {
    const int*   t        = (const int*)d_in[0];     // [B,T,1] int32
    const float* W1       = (const float*)d_in[1];   // [1,H]
    const float* b1       = (const float*)d_in[2];   // [H]
    const float* ln_g     = (const float*)d_in[3];   // [H]
    const float* ln_b     = (const float*)d_in[4];   // [H]
    const float* W2       = (const float*)d_in[5];   // [H,D]
    const float* b2       = (const float*)d_in[6];   // [D]
    const float* codebook = (const float*)d_in[7];   // [K,D]

    float* out      = (float*)d_out;
    float* out_q    = out;                     // Nt*Dc floats
    float* out_idx  = out + (size_t)Nt * Dc;   // Nt floats (idx as float)
    float* out_loss = out_idx + Nt;            // 1 float

    float* ws        = (float*)d_ws;
    float* q_table   = ws;                        // 512*64
    float* idxf_tab  = ws + Kc * Dc;              // 512
    float* d2_tab    = idxf_tab + Kc;             // 512
    float* partials  = d2_tab + Kc;               // 4096

    precompute_kernel<<<Kc, 256, 0, stream>>>(
        W1, b1, ln_g, ln_b, W2, b2, codebook,
        q_table, idxf_tab, d2_tab);

    qgather_kernel<<<QG_BLOCKS, QG_THREADS, 0, stream>>>(
        t, q_table, idxf_tab, d2_tab, out_q, out_idx, partials);

    loss_reduce_kernel<<<1, 256, 0, stream>>>(partials, out_loss);
}